// Round 9
// baseline (759.250 us; speedup 1.0000x reference)
//
#include <hip/hip_runtime.h>
#include <hip/hip_bf16.h>
#include <math.h>

#define NB   512        // queries
#define ND   64         // dim
#define NC   1000000    // candidates
#define TOPK 100
#define SAMP 8192       // sampled candidates for threshold (rows 0..8191)
#define SAMP_R 8        // take 8th largest of sample as threshold
#define CAP  4096       // survivor buffer per query
#define MARGIN 0.5f     // bf16-scoring safety margin
#define BM   128        // candidate rows per k1 tile
#define NT128 7813      // ceil(NC/BM)
#define K1GRID 1024     // 4 blocks/CU
#define QW   36         // per-wave queue capacity (window = 2 tiles, ~19.3 avg)

typedef __attribute__((ext_vector_type(8)))  short bf16x8;
typedef __attribute__((ext_vector_type(16))) float f32x16;

// f32 score with float4 loads; fma order d=0..63 IDENTICAL to the verified
// sequential chain (bit-matches np reference). Rows are 256B -> 16B aligned.
__device__ __forceinline__ float score_f32v(const float* __restrict__ c,
                                            const float* __restrict__ q)
{
    float s = 0.f;
    const float4* c4 = (const float4*)c;
#pragma unroll
    for (int i = 0; i < 16; ++i) {
        const float4 a = c4[i];
        s = fmaf(a.x, q[i * 4 + 0], s);
        s = fmaf(a.y, q[i * 4 + 1], s);
        s = fmaf(a.z, q[i * 4 + 2], s);
        s = fmaf(a.w, q[i * 4 + 3], s);
    }
    return s;
}

__device__ __forceinline__ unsigned int pack_bf16(float lo, float hi)
{
    unsigned int ul = __float_as_uint(lo), uh = __float_as_uint(hi);
    ul = (ul + 0x7fffu + ((ul >> 16) & 1u)) >> 16;   // RNE f32->bf16
    uh = (uh + 0x7fffu + ((uh >> 16) & 1u)) >> 16;
    return (uh << 16) | (ul & 0xffffu);
}

// Monotone f32 <-> uint mapping (order-preserving, handles negatives)
__device__ __forceinline__ unsigned fmap(float f)
{
    const unsigned u = __float_as_uint(f);
    return (u & 0x80000000u) ? ~u : (u | 0x80000000u);
}
__device__ __forceinline__ float funmap(unsigned m)
{
    return __uint_as_float((m & 0x80000000u) ? (m & 0x7fffffffu) : ~m);
}

// rank-th largest (1-based) of v[0..m). Exact (4x8-bit radix).
__device__ void radix_value_desc(const float* __restrict__ v, int m, int rank,
                                 int nthr, int tid,
                                 unsigned* hist, unsigned* cum, unsigned* bc,
                                 unsigned* out_mu, int* out_r, int* out_eq)
{
    unsigned pref = 0; int want = rank;
    for (int p = 24; p >= 0; p -= 8) {
        for (int b = tid; b < 256; b += nthr) hist[b] = 0;
        __syncthreads();
        for (int i = tid; i < m; i += nthr) {
            const unsigned mu = fmap(v[i]);
            if (p == 24 || ((mu >> (p + 8)) == (pref >> (p + 8))))
                atomicAdd(&hist[(mu >> p) & 255u], 1u);
        }
        __syncthreads();
        if (tid < 64) {   // suffix-scan cum[b] = sum_{b'>=b} hist[b']
            const unsigned h0 = hist[4*tid], h1 = hist[4*tid+1],
                           h2 = hist[4*tid+2], h3 = hist[4*tid+3];
            const unsigned g = h0 + h1 + h2 + h3;
            unsigned s = g;
#pragma unroll
            for (int off = 1; off < 64; off <<= 1) {
                const unsigned o = __shfl_down(s, off, 64);
                if (tid + off < 64) s += o;
            }
            const unsigned se = s - g;
            cum[4*tid+3] = h3 + se;
            cum[4*tid+2] = h2 + h3 + se;
            cum[4*tid+1] = h1 + h2 + h3 + se;
            cum[4*tid+0] = g + se;
        }
        __syncthreads();
        if (tid < 256) {
            const int c0 = (int)cum[tid];
            const int c1 = (tid == 255) ? 0 : (int)cum[tid + 1];
            if (c0 >= want && c1 < want) {
                bc[0] = pref | ((unsigned)tid << p);
                bc[1] = (unsigned)(want - c1);
                bc[2] = (unsigned)(c0 - c1);
            }
        }
        __syncthreads();
        pref = bc[0];
        want = (int)bc[1];
    }
    *out_mu = pref; *out_r = want; *out_eq = (int)bc[2];
}

// rank-th smallest (1-based) index among elements with fmap(v[i])==mustar.
__device__ int radix_index_asc(const float* __restrict__ v, const int* __restrict__ ix,
                               unsigned mustar, int m, int rank, int nthr, int tid,
                               unsigned* hist, unsigned* cum, unsigned* bc)
{
    unsigned pref = 0; int want = rank;
    for (int p = 16; p >= 0; p -= 8) {   // indices < 2^24
        for (int b = tid; b < 256; b += nthr) hist[b] = 0;
        __syncthreads();
        for (int i = tid; i < m; i += nthr) {
            if (fmap(v[i]) == mustar) {
                const unsigned k = (unsigned)ix[i];
                if (p == 16 || ((k >> (p + 8)) == (pref >> (p + 8))))
                    atomicAdd(&hist[(k >> p) & 255u], 1u);
            }
        }
        __syncthreads();
        if (tid < 64) {   // prefix-scan
            const unsigned h0 = hist[4*tid], h1 = hist[4*tid+1],
                           h2 = hist[4*tid+2], h3 = hist[4*tid+3];
            const unsigned g = h0 + h1 + h2 + h3;
            unsigned s = g;
#pragma unroll
            for (int off = 1; off < 64; off <<= 1) {
                const unsigned o = __shfl_up(s, off, 64);
                if ((int)tid - off >= 0) s += o;
            }
            const unsigned se = s - g;
            cum[4*tid+0] = se + h0;
            cum[4*tid+1] = se + h0 + h1;
            cum[4*tid+2] = se + h0 + h1 + h2;
            cum[4*tid+3] = se + g;
        }
        __syncthreads();
        if (tid < 256) {
            const int c0 = (int)cum[tid];
            const int cp = (tid == 0) ? 0 : (int)cum[tid - 1];
            if (c0 >= want && cp < want) {
                bc[0] = pref | ((unsigned)tid << p);
                bc[1] = (unsigned)(want - cp);
            }
        }
        __syncthreads();
        pref = bc[0];
        want = (int)bc[1];
    }
    return (int)pref;
}

// ---------------- KQ: one-shot Q f32 -> bf16 fragment-major ----------------
__global__ __launch_bounds__(256) void kq_pack(const float* __restrict__ qs,
                                               unsigned int* __restrict__ qbf)
{
    const int g = blockIdx.x * 256 + threadIdx.x;   // 4096 chunks
    if (g >= 4096) return;
    const int qrow = g >> 3, c = g & 7;
    const float* src = qs + qrow * ND + c * 8;
    const float4 f0 = *(const float4*)src;
    const float4 f1 = *(const float4*)(src + 4);
    const int chunk = (((qrow >> 5) * 4 + (c >> 1)) * 64) + (c & 1) * 32 + (qrow & 31);
    uint4 w;
    w.x = pack_bf16(f0.x, f0.y); w.y = pack_bf16(f0.z, f0.w);
    w.z = pack_bf16(f1.x, f1.y); w.w = pack_bf16(f1.z, f1.w);
    *(uint4*)(qbf + (size_t)chunk * 4) = w;
}

// ---------------- K0: per-query threshold via radix select -----------------
__global__ __launch_bounds__(512) void k0_sample(const float* __restrict__ qs,
                                                 const float* __restrict__ cs,
                                                 float* __restrict__ T)
{
    __shared__ float ls[SAMP];          // 32 KB sample scores
    __shared__ float lq[ND];
    __shared__ unsigned hist[256], cum[256], bc[4];
    const int qi = blockIdx.x;
    const int tid = threadIdx.x;
    if (tid < ND) lq[tid] = qs[qi * ND + tid];
    __syncthreads();
    for (int j = tid; j < SAMP; j += 512)
        ls[j] = score_f32v(cs + (size_t)j * ND, lq);
    __syncthreads();
    unsigned mustar; int r, eq;
    radix_value_desc(ls, SAMP, SAMP_R, 512, tid, hist, cum, bc, &mustar, &r, &eq);
    if (tid == 0) T[qi] = funmap(mustar);
}

// ---------------- K1: GEMM-style bf16 MFMA prune, per-wave LDS queues ------
__device__ __forceinline__ void k1_load(const float* __restrict__ cs, int t,
                                        float4* sreg, int tid)
{
#pragma unroll
    for (int i = 0; i < 2; ++i) {
        const int c = i * 512 + tid;          // 16B-chunk index in tile (1024 total)
        const int row = c >> 3, gp = c & 7;
        const int g = gp ^ (row & 7);         // inverse swizzle on SOURCE
        int gr = t * BM + row;
        if (gr >= NC) gr = 0;                 // clamp (epilogue filters n>=NC)
        const float* p = cs + (size_t)gr * ND + g * 8;
        sreg[2 * i]     = *(const float4*)p;
        sreg[2 * i + 1] = *(const float4*)(p + 4);
    }
}

__device__ __forceinline__ void k1_write(unsigned int* __restrict__ dst,
                                         const float4* sreg, int tid)
{
#pragma unroll
    for (int i = 0; i < 2; ++i) {
        const int c = i * 512 + tid;
        uint4 w;
        w.x = pack_bf16(sreg[2 * i].x,     sreg[2 * i].y);
        w.y = pack_bf16(sreg[2 * i].z,     sreg[2 * i].w);
        w.z = pack_bf16(sreg[2 * i + 1].x, sreg[2 * i + 1].y);
        w.w = pack_bf16(sreg[2 * i + 1].z, sreg[2 * i + 1].w);
        *(uint4*)(dst + (size_t)c * 4) = w;
    }
}

__global__ __launch_bounds__(512, 6) void k1_mfma(const unsigned int* __restrict__ qbf,
                                                  const float* __restrict__ cs,
                                                  const float* __restrict__ T,
                                                  unsigned int* __restrict__ cnt,
                                                  int* __restrict__ buf)
{
    __shared__ unsigned int alds[2][BM * 32];   // 2 x 16 KB swizzled bf16 tiles
    __shared__ uint2 qq[2][8][QW];              // per-wave double-buffered queues
    __shared__ unsigned int qcnt[2][8];
    const int tid = threadIdx.x;
    const int wave = tid >> 6, lane = tid & 63;
    const int arow = lane & 31, khalf = lane >> 5;

    if (tid < 16) qcnt[tid >> 3][tid & 7] = 0;

    // B-fragments: wave w owns queries [w*64, w*64+64), VGPR-resident
    bf16x8 bfr0[4], bfr1[4];
#pragma unroll
    for (int k0 = 0; k0 < 4; ++k0) {
        union { uint4 q; bf16x8 v; } u0, u1;
        u0.q = *(const uint4*)(qbf + (((size_t)(wave * 2 + 0) * 4 + k0) * 64 + lane) * 4);
        u1.q = *(const uint4*)(qbf + (((size_t)(wave * 2 + 1) * 4 + k0) * 64 + lane) * 4);
        bfr0[k0] = u0.v; bfr1[k0] = u1.v;
    }
    const int query0 = wave * 64 + arow;
    const int query1 = query0 + 32;
    const float tm0 = T[query0] - MARGIN;       // L2-hot, per-lane regs
    const float tm1 = T[query1] - MARGIN;

    float4 sreg[4];
    k1_load(cs, blockIdx.x, sreg, tid);
    k1_write(&alds[0][0], sreg, tid);
    __syncthreads();

    int cur = 0, qc = 0, ip = 0;
    for (int t = blockIdx.x; t < NT128; t += K1GRID) {
        const int tn = t + K1GRID;
        const bool hn = (tn < NT128);
        if (hn) k1_load(cs, tn, sreg, tid);          // issue loads early (T14)

        const unsigned int* a = &alds[cur][0];
        uint2* qb = qq[qc][wave];
        unsigned int* qcp = &qcnt[qc][wave];
#pragma unroll
        for (int st = 0; st < 4; ++st) {
            const int r0 = st * 32 + arow;
            bf16x8 af[4];
#pragma unroll
            for (int k0 = 0; k0 < 4; ++k0) {
                const int g = (k0 * 2 + khalf) ^ (r0 & 7);
                union { uint4 q; bf16x8 v; } u;
                u.q = *(const uint4*)(a + ((size_t)r0 * 8 + g) * 4);
                af[k0] = u.v;
            }
            f32x16 acc0, acc1;
#pragma unroll
            for (int i = 0; i < 16; ++i) { acc0[i] = 0.f; acc1[i] = 0.f; }
#pragma unroll
            for (int k0 = 0; k0 < 4; ++k0) {
                acc0 = __builtin_amdgcn_mfma_f32_32x32x16_bf16(af[k0], bfr0[k0], acc0, 0, 0, 0);
                acc1 = __builtin_amdgcn_mfma_f32_32x32x16_bf16(af[k0], bfr1[k0], acc1, 0, 0, 0);
            }
#pragma unroll
            for (int r = 0; r < 16; ++r) {
                const int n = t * BM + st * 32 + (r & 3) + 8 * (r >> 2) + 4 * khalf;
                if (acc0[r] >= tm0 && n < NC) {
                    const unsigned int qp = atomicAdd(qcp, 1u);
                    if (qp < QW) qb[qp] = make_uint2((unsigned)query0, (unsigned)n);
                    else { const unsigned int p = atomicAdd(&cnt[query0], 1u);
                           if (p < CAP) buf[(size_t)query0 * CAP + p] = n; }
                }
                if (acc1[r] >= tm1 && n < NC) {
                    const unsigned int qp = atomicAdd(qcp, 1u);
                    if (qp < QW) qb[qp] = make_uint2((unsigned)query1, (unsigned)n);
                    else { const unsigned int p = atomicAdd(&cnt[query1], 1u);
                           if (p < CAP) buf[(size_t)query1 * CAP + p] = n; }
                }
            }
        }
        __syncthreads();                              // A: pushes + LDS reads done
        const bool dodrain = ip || !hn;               // every 2nd tile, and last
        if (dodrain) {
            if (tid < 8) qcnt[qc ^ 1][tid] = 0;       // reset OTHER buffer's counters
            if (tid < 8 * QW) {                       // one-pass parallel drain
                const int w = tid / QW, j = tid % QW;
                const unsigned int qn = qcnt[qc][w];
                if ((unsigned)j < (qn < QW ? qn : QW)) {
                    const uint2 e = qq[qc][w][j];
                    const unsigned int p = atomicAdd(&cnt[e.x], 1u);
                    if (p < CAP) buf[(size_t)e.x * CAP + p] = (int)e.y;
                }
            }
        }
        if (hn) k1_write(&alds[cur ^ 1][0], sreg, tid);
        __syncthreads();                              // C: drain + write done
        cur ^= 1;
        if (dodrain) { qc ^= 1; ip = 0; } else ip = 1;
    }
}

// ---------------- K2: exact f32 rescore + radix top-K ----------------------
__device__ __forceinline__ bool prec(float av, int ai, float bv, int bi)
{
    return (av > bv) || (av == bv && ai < bi);
}

__device__ void bitonic_desc(float* v, int* ix, int n, int tid, int nthr)
{
    for (int k = 2; k <= n; k <<= 1) {
        for (int j = k >> 1; j > 0; j >>= 1) {
            for (int i = tid; i < n; i += nthr) {
                int p = i ^ j;
                if (p > i) {
                    bool swap_;
                    if ((i & k) == 0) swap_ = prec(v[p], ix[p], v[i], ix[i]);
                    else              swap_ = prec(v[i], ix[i], v[p], ix[p]);
                    if (swap_) {
                        float tv_ = v[i]; v[i] = v[p]; v[p] = tv_;
                        int   ti_ = ix[i]; ix[i] = ix[p]; ix[p] = ti_;
                    }
                }
            }
            __syncthreads();
        }
    }
}

__global__ __launch_bounds__(1024) void k2_final(const float* __restrict__ qs,
                                                 const float* __restrict__ cs,
                                                 const unsigned int* __restrict__ cnt,
                                                 const int* __restrict__ buf,
                                                 float* __restrict__ out)
{
    __shared__ float sv[CAP];
    __shared__ int   si[CAP];
    __shared__ float lq[ND];
    __shared__ unsigned hist[256], cum[256], bc[4];
    __shared__ float fv[128];
    __shared__ int   fi[128];
    __shared__ float tv[128];
    __shared__ int   ti[128];
    const int qi = blockIdx.x;
    const int tid = threadIdx.x;
    if (tid < ND) lq[tid] = qs[qi * ND + tid];
    __syncthreads();
    const unsigned int c = cnt[qi];
    const bool fix = (c < TOPK) || (c > CAP);
    if (!fix) {
        const int m = (int)c;
        for (int i = tid; i < m; i += 1024) {
            const int n = buf[(size_t)qi * CAP + i];
            sv[i] = score_f32v(cs + (size_t)n * ND, lq);
            si[i] = n;
        }
        __syncthreads();
        unsigned mustar; int r, eq;
        radix_value_desc(sv, m, TOPK, 1024, tid, hist, cum, bc, &mustar, &r, &eq);
        int idxstar = 0x7fffffff;
        if (r < eq)
            idxstar = radix_index_asc(sv, si, mustar, m, r, 1024, tid, hist, cum, bc);
        if (tid == 0) bc[3] = 0;
        __syncthreads();
        for (int i = tid; i < m; i += 1024) {
            const unsigned mu = fmap(sv[i]);
            if (mu > mustar || (mu == mustar && si[i] <= idxstar)) {
                const unsigned p = atomicAdd(&bc[3], 1u);
                if (p < 128) { fv[p] = sv[i]; fi[p] = si[i]; }
            }
        }
        __syncthreads();
        for (int i = tid; i < 128; i += 1024)
            if (i >= TOPK) { fv[i] = -INFINITY; fi[i] = 0x7fffffff; }
        __syncthreads();
        bitonic_desc(fv, fi, 128, tid, 1024);
        for (int j = tid; j < TOPK; j += 1024) {
            out[qi * TOPK + j] = fv[j];
            out[NB * TOPK + qi * TOPK + j] = (float)fi[j];
        }
    } else {
        // exact fallback (rare): chunked full scan with carried top-128
        for (int i = tid; i < 128; i += 1024) { tv[i] = -INFINITY; ti[i] = 0x7fffffff; }
        __syncthreads();
        const int CH = CAP - 128;
        for (int base = 0; base < NC; base += CH) {
            for (int i = tid; i < CAP; i += 1024) {
                if (i < 128) { sv[i] = tv[i]; si[i] = ti[i]; }
                else {
                    const int n = base + (i - 128);
                    if (n < NC) {
                        sv[i] = score_f32v(cs + (size_t)n * ND, lq);
                        si[i] = n;
                    } else { sv[i] = -INFINITY; si[i] = 0x7fffffff; }
                }
            }
            __syncthreads();
            bitonic_desc(sv, si, CAP, tid, 1024);
            for (int i = tid; i < 128; i += 1024) { tv[i] = sv[i]; ti[i] = si[i]; }
            __syncthreads();
        }
        for (int j = tid; j < TOPK; j += 1024) {
            out[qi * TOPK + j] = tv[j];
            out[NB * TOPK + qi * TOPK + j] = (float)ti[j];
        }
    }
}

extern "C" void kernel_launch(void* const* d_in, const int* in_sizes, int n_in,
                              void* d_out, int out_size, void* d_ws, size_t ws_size,
                              hipStream_t stream)
{
    const float* qs = (const float*)d_in[0];
    const float* cs = (const float*)d_in[1];
    float*        T   = (float*)d_ws;                                  // 2 KB
    unsigned int* cnt = (unsigned int*)((char*)d_ws + 2048);           // 2 KB
    unsigned int* qbf = (unsigned int*)((char*)d_ws + 4096);           // 64 KB
    int*          buf = (int*)((char*)d_ws + 4096 + 65536);            // 8 MB
    float* out = (float*)d_out;

    hipMemsetAsync(cnt, 0, NB * sizeof(unsigned int), stream);
    kq_pack<<<16, 256, 0, stream>>>(qs, qbf);
    k0_sample<<<NB, 512, 0, stream>>>(qs, cs, T);
    k1_mfma<<<K1GRID, 512, 0, stream>>>(qbf, cs, T, cnt, buf);
    k2_final<<<NB, 1024, 0, stream>>>(qs, cs, cnt, buf, out);
}

// Round 10
// 502.574 us; speedup vs baseline: 1.5107x; 1.5107x over previous
//
#include <hip/hip_runtime.h>
#include <hip/hip_bf16.h>
#include <math.h>

#define NB   512        // queries
#define ND   64         // dim
#define NC   1000000    // candidates
#define TOPK 100
#define SAMP 8192       // sampled candidates for threshold (rows 0..8191)
#define SAMP_R 8        // take 8th largest of sample as threshold
#define CAP  4096       // survivor buffer per query
#define MARGIN 0.5f     // bf16-scoring safety margin
#define BM   128        // candidate rows per k1 tile
#define NT128 7813      // ceil(NC/BM)
#define K1GRID 512      // 2 blocks/CU at <=128 regs
#define QW   36         // per-wave queue capacity (window = 2 tiles, ~0.6 avg)

typedef __attribute__((ext_vector_type(8)))  short bf16x8;
typedef __attribute__((ext_vector_type(16))) float f32x16;

// f32 score with float4 loads; fma order d=0..63 IDENTICAL to the verified
// sequential chain (bit-matches np reference). Rows are 256B -> 16B aligned.
__device__ __forceinline__ float score_f32v(const float* __restrict__ c,
                                            const float* __restrict__ q)
{
    float s = 0.f;
    const float4* c4 = (const float4*)c;
#pragma unroll
    for (int i = 0; i < 16; ++i) {
        const float4 a = c4[i];
        s = fmaf(a.x, q[i * 4 + 0], s);
        s = fmaf(a.y, q[i * 4 + 1], s);
        s = fmaf(a.z, q[i * 4 + 2], s);
        s = fmaf(a.w, q[i * 4 + 3], s);
    }
    return s;
}

__device__ __forceinline__ unsigned int pack_bf16(float lo, float hi)
{
    unsigned int ul = __float_as_uint(lo), uh = __float_as_uint(hi);
    ul = (ul + 0x7fffu + ((ul >> 16) & 1u)) >> 16;   // RNE f32->bf16
    uh = (uh + 0x7fffu + ((uh >> 16) & 1u)) >> 16;
    return (uh << 16) | (ul & 0xffffu);
}

// Monotone f32 <-> uint mapping (order-preserving, handles negatives)
__device__ __forceinline__ unsigned fmap(float f)
{
    const unsigned u = __float_as_uint(f);
    return (u & 0x80000000u) ? ~u : (u | 0x80000000u);
}
__device__ __forceinline__ float funmap(unsigned m)
{
    return __uint_as_float((m & 0x80000000u) ? (m & 0x7fffffffu) : ~m);
}

// rank-th largest (1-based) of v[0..m). Exact (4x8-bit radix).
__device__ void radix_value_desc(const float* __restrict__ v, int m, int rank,
                                 int nthr, int tid,
                                 unsigned* hist, unsigned* cum, unsigned* bc,
                                 unsigned* out_mu, int* out_r, int* out_eq)
{
    unsigned pref = 0; int want = rank;
    for (int p = 24; p >= 0; p -= 8) {
        for (int b = tid; b < 256; b += nthr) hist[b] = 0;
        __syncthreads();
        for (int i = tid; i < m; i += nthr) {
            const unsigned mu = fmap(v[i]);
            if (p == 24 || ((mu >> (p + 8)) == (pref >> (p + 8))))
                atomicAdd(&hist[(mu >> p) & 255u], 1u);
        }
        __syncthreads();
        if (tid < 64) {   // suffix-scan cum[b] = sum_{b'>=b} hist[b']
            const unsigned h0 = hist[4*tid], h1 = hist[4*tid+1],
                           h2 = hist[4*tid+2], h3 = hist[4*tid+3];
            const unsigned g = h0 + h1 + h2 + h3;
            unsigned s = g;
#pragma unroll
            for (int off = 1; off < 64; off <<= 1) {
                const unsigned o = __shfl_down(s, off, 64);
                if (tid + off < 64) s += o;
            }
            const unsigned se = s - g;
            cum[4*tid+3] = h3 + se;
            cum[4*tid+2] = h2 + h3 + se;
            cum[4*tid+1] = h1 + h2 + h3 + se;
            cum[4*tid+0] = g + se;
        }
        __syncthreads();
        if (tid < 256) {
            const int c0 = (int)cum[tid];
            const int c1 = (tid == 255) ? 0 : (int)cum[tid + 1];
            if (c0 >= want && c1 < want) {
                bc[0] = pref | ((unsigned)tid << p);
                bc[1] = (unsigned)(want - c1);
                bc[2] = (unsigned)(c0 - c1);
            }
        }
        __syncthreads();
        pref = bc[0];
        want = (int)bc[1];
    }
    *out_mu = pref; *out_r = want; *out_eq = (int)bc[2];
}

// rank-th smallest (1-based) index among elements with fmap(v[i])==mustar.
__device__ int radix_index_asc(const float* __restrict__ v, const int* __restrict__ ix,
                               unsigned mustar, int m, int rank, int nthr, int tid,
                               unsigned* hist, unsigned* cum, unsigned* bc)
{
    unsigned pref = 0; int want = rank;
    for (int p = 16; p >= 0; p -= 8) {   // indices < 2^24
        for (int b = tid; b < 256; b += nthr) hist[b] = 0;
        __syncthreads();
        for (int i = tid; i < m; i += nthr) {
            if (fmap(v[i]) == mustar) {
                const unsigned k = (unsigned)ix[i];
                if (p == 16 || ((k >> (p + 8)) == (pref >> (p + 8))))
                    atomicAdd(&hist[(k >> p) & 255u], 1u);
            }
        }
        __syncthreads();
        if (tid < 64) {   // prefix-scan
            const unsigned h0 = hist[4*tid], h1 = hist[4*tid+1],
                           h2 = hist[4*tid+2], h3 = hist[4*tid+3];
            const unsigned g = h0 + h1 + h2 + h3;
            unsigned s = g;
#pragma unroll
            for (int off = 1; off < 64; off <<= 1) {
                const unsigned o = __shfl_up(s, off, 64);
                if ((int)tid - off >= 0) s += o;
            }
            const unsigned se = s - g;
            cum[4*tid+0] = se + h0;
            cum[4*tid+1] = se + h0 + h1;
            cum[4*tid+2] = se + h0 + h1 + h2;
            cum[4*tid+3] = se + g;
        }
        __syncthreads();
        if (tid < 256) {
            const int c0 = (int)cum[tid];
            const int cp = (tid == 0) ? 0 : (int)cum[tid - 1];
            if (c0 >= want && cp < want) {
                bc[0] = pref | ((unsigned)tid << p);
                bc[1] = (unsigned)(want - cp);
            }
        }
        __syncthreads();
        pref = bc[0];
        want = (int)bc[1];
    }
    return (int)pref;
}

// ---------------- KQ: one-shot Q f32 -> bf16 fragment-major ----------------
__global__ __launch_bounds__(256) void kq_pack(const float* __restrict__ qs,
                                               unsigned int* __restrict__ qbf)
{
    const int g = blockIdx.x * 256 + threadIdx.x;   // 4096 chunks
    if (g >= 4096) return;
    const int qrow = g >> 3, c = g & 7;
    const float* src = qs + qrow * ND + c * 8;
    const float4 f0 = *(const float4*)src;
    const float4 f1 = *(const float4*)(src + 4);
    const int chunk = (((qrow >> 5) * 4 + (c >> 1)) * 64) + (c & 1) * 32 + (qrow & 31);
    uint4 w;
    w.x = pack_bf16(f0.x, f0.y); w.y = pack_bf16(f0.z, f0.w);
    w.z = pack_bf16(f1.x, f1.y); w.w = pack_bf16(f1.z, f1.w);
    *(uint4*)(qbf + (size_t)chunk * 4) = w;
}

// ---------------- K0: per-query threshold via radix select -----------------
__global__ __launch_bounds__(512) void k0_sample(const float* __restrict__ qs,
                                                 const float* __restrict__ cs,
                                                 float* __restrict__ T)
{
    __shared__ float ls[SAMP];          // 32 KB sample scores
    __shared__ float lq[ND];
    __shared__ unsigned hist[256], cum[256], bc[4];
    const int qi = blockIdx.x;
    const int tid = threadIdx.x;
    if (tid < ND) lq[tid] = qs[qi * ND + tid];
    __syncthreads();
    for (int j = tid; j < SAMP; j += 512)
        ls[j] = score_f32v(cs + (size_t)j * ND, lq);
    __syncthreads();
    unsigned mustar; int r, eq;
    radix_value_desc(ls, SAMP, SAMP_R, 512, tid, hist, cum, bc, &mustar, &r, &eq);
    if (tid == 0) T[qi] = funmap(mustar);
}

// ---------------- K1: GEMM-style bf16 MFMA prune, branch-free epilogue -----
__device__ __forceinline__ void k1_load(const float* __restrict__ cs, int t,
                                        float4* sreg, int tid)
{
#pragma unroll
    for (int i = 0; i < 2; ++i) {
        const int c = i * 512 + tid;          // 16B-chunk index in tile (1024 total)
        const int row = c >> 3, gp = c & 7;
        const int g = gp ^ (row & 7);         // inverse swizzle on SOURCE
        int gr = t * BM + row;
        if (gr >= NC) gr = 0;                 // clamp (epilogue filters n>=NC)
        const float* p = cs + (size_t)gr * ND + g * 8;
        sreg[2 * i]     = *(const float4*)p;
        sreg[2 * i + 1] = *(const float4*)(p + 4);
    }
}

__device__ __forceinline__ void k1_write(unsigned int* __restrict__ dst,
                                         const float4* sreg, int tid)
{
#pragma unroll
    for (int i = 0; i < 2; ++i) {
        const int c = i * 512 + tid;
        uint4 w;
        w.x = pack_bf16(sreg[2 * i].x,     sreg[2 * i].y);
        w.y = pack_bf16(sreg[2 * i].z,     sreg[2 * i].w);
        w.z = pack_bf16(sreg[2 * i + 1].x, sreg[2 * i + 1].y);
        w.w = pack_bf16(sreg[2 * i + 1].z, sreg[2 * i + 1].w);
        *(uint4*)(dst + (size_t)c * 4) = w;
    }
}

__global__ __launch_bounds__(512, 4) void k1_mfma(const unsigned int* __restrict__ qbf,
                                                  const float* __restrict__ cs,
                                                  const float* __restrict__ T,
                                                  unsigned int* __restrict__ cnt,
                                                  int* __restrict__ buf)
{
    __shared__ unsigned int alds[2][BM * 32];   // 2 x 16 KB swizzled bf16 tiles
    __shared__ uint2 qq[2][8][QW];              // per-wave double-buffered queues
    __shared__ unsigned int qcnt[2][8];
    const int tid = threadIdx.x;
    const int wave = tid >> 6, lane = tid & 63;
    const int arow = lane & 31, khalf = lane >> 5;

    if (tid < 16) qcnt[tid >> 3][tid & 7] = 0;

    // B-fragments: wave w owns queries [w*64, w*64+64), VGPR-resident
    bf16x8 bfr0[4], bfr1[4];
#pragma unroll
    for (int k0 = 0; k0 < 4; ++k0) {
        union { uint4 q; bf16x8 v; } u0, u1;
        u0.q = *(const uint4*)(qbf + (((size_t)(wave * 2 + 0) * 4 + k0) * 64 + lane) * 4);
        u1.q = *(const uint4*)(qbf + (((size_t)(wave * 2 + 1) * 4 + k0) * 64 + lane) * 4);
        bfr0[k0] = u0.v; bfr1[k0] = u1.v;
    }
    const int query0 = wave * 64 + arow;
    const int query1 = query0 + 32;
    const float tm0 = T[query0] - MARGIN;
    const float tm1 = T[query1] - MARGIN;

    float4 sreg[4];
    k1_load(cs, blockIdx.x, sreg, tid);
    k1_write(&alds[0][0], sreg, tid);
    __syncthreads();

    int cur = 0, qc = 0, ip = 0;
    for (int t = blockIdx.x; t < NT128; t += K1GRID) {
        const int tn = t + K1GRID;
        const bool hn = (tn < NT128);
        if (hn) k1_load(cs, tn, sreg, tid);          // issue loads early (T14)

        const unsigned int* a = &alds[cur][0];
        uint2* qb = qq[qc][wave];
        unsigned int* qcp = &qcnt[qc][wave];
#pragma unroll
        for (int st = 0; st < 4; ++st) {
            const int r0 = st * 32 + arow;
            bf16x8 af[4];
#pragma unroll
            for (int k0 = 0; k0 < 4; ++k0) {
                const int g = (k0 * 2 + khalf) ^ (r0 & 7);
                union { uint4 q; bf16x8 v; } u;
                u.q = *(const uint4*)(a + ((size_t)r0 * 8 + g) * 4);
                af[k0] = u.v;
            }
            f32x16 acc0, acc1;
#pragma unroll
            for (int i = 0; i < 16; ++i) { acc0[i] = 0.f; acc1[i] = 0.f; }
#pragma unroll
            for (int k0 = 0; k0 < 4; ++k0) {
                acc0 = __builtin_amdgcn_mfma_f32_32x32x16_bf16(af[k0], bfr0[k0], acc0, 0, 0, 0);
                acc1 = __builtin_amdgcn_mfma_f32_32x32x16_bf16(af[k0], bfr1[k0], acc1, 0, 0, 0);
            }
            // branch-free survivor detect: fmax tree, one rare branch
            float mx0 = acc0[0], mx1 = acc1[0];
#pragma unroll
            for (int r = 1; r < 16; ++r) {
                mx0 = fmaxf(mx0, acc0[r]);
                mx1 = fmaxf(mx1, acc1[r]);
            }
            if (mx0 >= tm0 || mx1 >= tm1) {          // ~0.5% of lanes
                unsigned m0 = 0u, m1 = 0u;
#pragma unroll
                for (int r = 0; r < 16; ++r) {
                    m0 |= (acc0[r] >= tm0) ? (1u << r) : 0u;
                    m1 |= (acc1[r] >= tm1) ? (1u << r) : 0u;
                }
                while (m0) {
                    const int r = __builtin_ctz(m0); m0 &= m0 - 1u;
                    const int n = t * BM + st * 32 + (r & 3) + 8 * (r >> 2) + 4 * khalf;
                    if (n < NC) {
                        const unsigned qp = atomicAdd(qcp, 1u);
                        if (qp < QW) qb[qp] = make_uint2((unsigned)query0, (unsigned)n);
                        else { const unsigned p = atomicAdd(&cnt[query0], 1u);
                               if (p < CAP) buf[(size_t)query0 * CAP + p] = n; }
                    }
                }
                while (m1) {
                    const int r = __builtin_ctz(m1); m1 &= m1 - 1u;
                    const int n = t * BM + st * 32 + (r & 3) + 8 * (r >> 2) + 4 * khalf;
                    if (n < NC) {
                        const unsigned qp = atomicAdd(qcp, 1u);
                        if (qp < QW) qb[qp] = make_uint2((unsigned)query1, (unsigned)n);
                        else { const unsigned p = atomicAdd(&cnt[query1], 1u);
                               if (p < CAP) buf[(size_t)query1 * CAP + p] = n; }
                    }
                }
            }
        }
        __syncthreads();                              // A: pushes + LDS reads done
        const bool dodrain = ip || !hn;               // every 2nd tile, and last
        if (dodrain) {
            if (tid < 8) qcnt[qc ^ 1][tid] = 0;       // reset OTHER buffer's counters
            if (tid < 8 * QW) {                       // one-pass parallel drain
                const int w = tid / QW, j = tid % QW;
                const unsigned int qn = qcnt[qc][w];
                if ((unsigned)j < (qn < QW ? qn : QW)) {
                    const uint2 e = qq[qc][w][j];
                    const unsigned int p = atomicAdd(&cnt[e.x], 1u);
                    if (p < CAP) buf[(size_t)e.x * CAP + p] = (int)e.y;
                }
            }
        }
        if (hn) k1_write(&alds[cur ^ 1][0], sreg, tid);
        __syncthreads();                              // C: drain + write done
        cur ^= 1;
        if (dodrain) { qc ^= 1; ip = 0; } else ip = 1;
    }
}

// ---------------- K2: exact f32 rescore + radix top-K ----------------------
__device__ __forceinline__ bool prec(float av, int ai, float bv, int bi)
{
    return (av > bv) || (av == bv && ai < bi);
}

__device__ void bitonic_desc(float* v, int* ix, int n, int tid, int nthr)
{
    for (int k = 2; k <= n; k <<= 1) {
        for (int j = k >> 1; j > 0; j >>= 1) {
            for (int i = tid; i < n; i += nthr) {
                int p = i ^ j;
                if (p > i) {
                    bool swap_;
                    if ((i & k) == 0) swap_ = prec(v[p], ix[p], v[i], ix[i]);
                    else              swap_ = prec(v[i], ix[i], v[p], ix[p]);
                    if (swap_) {
                        float tv_ = v[i]; v[i] = v[p]; v[p] = tv_;
                        int   ti_ = ix[i]; ix[i] = ix[p]; ix[p] = ti_;
                    }
                }
            }
            __syncthreads();
        }
    }
}

__global__ __launch_bounds__(1024) void k2_final(const float* __restrict__ qs,
                                                 const float* __restrict__ cs,
                                                 const unsigned int* __restrict__ cnt,
                                                 const int* __restrict__ buf,
                                                 float* __restrict__ out)
{
    __shared__ float sv[CAP];
    __shared__ int   si[CAP];
    __shared__ float lq[ND];
    __shared__ unsigned hist[256], cum[256], bc[4];
    __shared__ float fv[128];
    __shared__ int   fi[128];
    __shared__ float tv[128];
    __shared__ int   ti[128];
    const int qi = blockIdx.x;
    const int tid = threadIdx.x;
    if (tid < ND) lq[tid] = qs[qi * ND + tid];
    __syncthreads();
    const unsigned int c = cnt[qi];
    const bool fix = (c < TOPK) || (c > CAP);
    if (!fix) {
        const int m = (int)c;
        for (int i = tid; i < m; i += 1024) {
            const int n = buf[(size_t)qi * CAP + i];
            sv[i] = score_f32v(cs + (size_t)n * ND, lq);
            si[i] = n;
        }
        __syncthreads();
        unsigned mustar; int r, eq;
        radix_value_desc(sv, m, TOPK, 1024, tid, hist, cum, bc, &mustar, &r, &eq);
        int idxstar = 0x7fffffff;
        if (r < eq)
            idxstar = radix_index_asc(sv, si, mustar, m, r, 1024, tid, hist, cum, bc);
        if (tid == 0) bc[3] = 0;
        __syncthreads();
        for (int i = tid; i < m; i += 1024) {
            const unsigned mu = fmap(sv[i]);
            if (mu > mustar || (mu == mustar && si[i] <= idxstar)) {
                const unsigned p = atomicAdd(&bc[3], 1u);
                if (p < 128) { fv[p] = sv[i]; fi[p] = si[i]; }
            }
        }
        __syncthreads();
        for (int i = tid; i < 128; i += 1024)
            if (i >= TOPK) { fv[i] = -INFINITY; fi[i] = 0x7fffffff; }
        __syncthreads();
        bitonic_desc(fv, fi, 128, tid, 1024);
        for (int j = tid; j < TOPK; j += 1024) {
            out[qi * TOPK + j] = fv[j];
            out[NB * TOPK + qi * TOPK + j] = (float)fi[j];
        }
    } else {
        // exact fallback (rare): chunked full scan with carried top-128
        for (int i = tid; i < 128; i += 1024) { tv[i] = -INFINITY; ti[i] = 0x7fffffff; }
        __syncthreads();
        const int CH = CAP - 128;
        for (int base = 0; base < NC; base += CH) {
            for (int i = tid; i < CAP; i += 1024) {
                if (i < 128) { sv[i] = tv[i]; si[i] = ti[i]; }
                else {
                    const int n = base + (i - 128);
                    if (n < NC) {
                        sv[i] = score_f32v(cs + (size_t)n * ND, lq);
                        si[i] = n;
                    } else { sv[i] = -INFINITY; si[i] = 0x7fffffff; }
                }
            }
            __syncthreads();
            bitonic_desc(sv, si, CAP, tid, 1024);
            for (int i = tid; i < 128; i += 1024) { tv[i] = sv[i]; ti[i] = si[i]; }
            __syncthreads();
        }
        for (int j = tid; j < TOPK; j += 1024) {
            out[qi * TOPK + j] = tv[j];
            out[NB * TOPK + qi * TOPK + j] = (float)ti[j];
        }
    }
}

extern "C" void kernel_launch(void* const* d_in, const int* in_sizes, int n_in,
                              void* d_out, int out_size, void* d_ws, size_t ws_size,
                              hipStream_t stream)
{
    const float* qs = (const float*)d_in[0];
    const float* cs = (const float*)d_in[1];
    float*        T   = (float*)d_ws;                                  // 2 KB
    unsigned int* cnt = (unsigned int*)((char*)d_ws + 2048);           // 2 KB
    unsigned int* qbf = (unsigned int*)((char*)d_ws + 4096);           // 64 KB
    int*          buf = (int*)((char*)d_ws + 4096 + 65536);            // 8 MB
    float* out = (float*)d_out;

    hipMemsetAsync(cnt, 0, NB * sizeof(unsigned int), stream);
    kq_pack<<<16, 256, 0, stream>>>(qs, qbf);
    k0_sample<<<NB, 512, 0, stream>>>(qs, cs, T);
    k1_mfma<<<K1GRID, 512, 0, stream>>>(qbf, cs, T, cnt, buf);
    k2_final<<<NB, 1024, 0, stream>>>(qs, cs, cnt, buf, out);
}